// Round 6
// baseline (395.179 us; speedup 1.0000x reference)
//
#include <hip/hip_runtime.h>
#include <hip/hip_bf16.h>
#include <math.h>

#define H_ 64
#define W_ 64
#define CIN 128
#define COUT 256
#define NB 8
#define KK9 9
#define NPIX 4096        // H_*W_
#define KTOT 1152        // CIN*KK9
#define NCK 36           // K chunks of 32 (kk-major: k' = kk*128 + c)
#define SPAD 40          // S K-row pad (shorts): 80B rows, 2-way bank alias = free

typedef short short8_t __attribute__((ext_vector_type(8)));
typedef float floatx4 __attribute__((ext_vector_type(4)));

__device__ __forceinline__ unsigned short f2bf(float f) {
    union { float f; unsigned u; } v; v.f = f;
    unsigned r = v.u + 0x7FFF + ((v.u >> 16) & 1);   // RNE
    return (unsigned short)(r >> 16);
}
__device__ __forceinline__ float bf2f(unsigned short h) {
    union { unsigned u; float f; } v; v.u = ((unsigned)h) << 16;
    return v.f;
}

#if defined(__has_builtin)
#if __has_builtin(__builtin_amdgcn_global_load_lds)
#define HAVE_GLOAD_LDS 1
#endif
#endif

#ifdef HAVE_GLOAD_LDS
__device__ __forceinline__ void gload_lds16(const unsigned short* g, unsigned short* l) {
    __builtin_amdgcn_global_load_lds(
        (const __attribute__((address_space(1))) unsigned int*)g,
        (__attribute__((address_space(3))) unsigned int*)l, 16, 0, 0);
}
#endif

#define SBAR()   __builtin_amdgcn_s_barrier()
#define SCHED0() __builtin_amdgcn_sched_barrier(0)
#define WAIT_LGKM0() asm volatile("s_waitcnt lgkmcnt(0)" ::: "memory")
#define WAIT_VM0()   asm volatile("s_waitcnt vmcnt(0)"   ::: "memory")

// ---------------------------------------------------------------------------
// Kernel A: offset conv (18 ch) + modulation conv (9 ch), fused (fp32 direct).
// Change this round: weight taps read as b128 pairs into static wt[9]
// (was 18 scalar ds_read_b32 per (c,chpair) -> LDS-unit bound).
// ---------------------------------------------------------------------------
__global__ __launch_bounds__(256) void k_offmod(
    const float* __restrict__ x, const float* __restrict__ w_off,
    const float* __restrict__ b_off, const float* __restrict__ w_mod,
    const float* __restrict__ b_mod, float* __restrict__ ppy,
    float* __restrict__ ppx, float* __restrict__ pmod)
{
    __shared__ float xp[16][10][12];
    __shared__ float wb[27][16][12];
    const int t = threadIdx.x;
    const int tx = blockIdx.x, ty = blockIdx.y, b = blockIdx.z;
    const int q = t & 15, g = t >> 4;
    const int lpy = q >> 1, lpx4 = (q & 1) * 4;
    float acc[2][4] = {};

    for (int cc = 0; cc < CIN; cc += 16) {
        __syncthreads();
        for (int idx = t; idx < 1600; idx += 256) {
            int c = idx / 100, r = (idx % 100) / 10, col = idx % 10;
            int gy = ty * 8 - 1 + r, gx = tx * 8 - 1 + col;
            float v = 0.f;
            if (gy >= 0 && gy < H_ && gx >= 0 && gx < W_)
                v = x[((b * CIN + cc + c) * H_ + gy) * W_ + gx];
            xp[c][r][col] = v;
        }
        for (int idx = t; idx < 27 * 16 * 9; idx += 256) {
            int ch = idx / 144, rr = idx % 144, c = rr / 9, tap = rr % 9;
            wb[ch][c][tap] = (ch < 18)
                ? w_off[(ch * CIN + cc + c) * 9 + tap]
                : w_mod[((ch - 18) * CIN + cc + c) * 9 + tap];
        }
        __syncthreads();

        for (int c = 0; c < 16; ++c) {
            float xv[3][8];
            #pragma unroll
            for (int ky = 0; ky < 3; ++ky) {
                float4 v0 = *(const float4*)&xp[c][lpy + ky][lpx4];
                float4 v1 = *(const float4*)&xp[c][lpy + ky][lpx4 + 4];
                xv[ky][0] = v0.x; xv[ky][1] = v0.y; xv[ky][2] = v0.z; xv[ky][3] = v0.w;
                xv[ky][4] = v1.x; xv[ky][5] = v1.y; xv[ky][6] = v1.z; xv[ky][7] = v1.w;
            }
            #pragma unroll
            for (int i = 0; i < 2; ++i) {
                int ch = g + 16 * i;
                if (ch < 27) {
                    // batched weight read: 2x b128 + 1x b32 (wb rows are 48B -> aligned)
                    float4 wa = *(const float4*)&wb[ch][c][0];
                    float4 wv4 = *(const float4*)&wb[ch][c][4];
                    float w8 = wb[ch][c][8];
                    float wt[9] = {wa.x, wa.y, wa.z, wa.w,
                                   wv4.x, wv4.y, wv4.z, wv4.w, w8};
                    #pragma unroll
                    for (int ky = 0; ky < 3; ++ky)
                        #pragma unroll
                        for (int kx = 0; kx < 3; ++kx) {
                            float wv = wt[ky * 3 + kx];
                            #pragma unroll
                            for (int p = 0; p < 4; ++p)
                                acc[i][p] += xv[ky][p + kx] * wv;
                        }
                }
            }
        }
    }

    const int ho = ty * 8 + lpy;
    #pragma unroll
    for (int i = 0; i < 2; ++i) {
        int ch = g + 16 * i;
        if (ch >= 27) continue;
        #pragma unroll
        for (int p = 0; p < 4; ++p) {
            int wo = tx * 8 + lpx4 + p;
            int pix = ho * W_ + wo;
            if (ch < 18) {
                float v = acc[i][p] + b_off[ch];
                int kk = ch >> 1;
                if ((ch & 1) == 0)
                    ppy[(b * KK9 + kk) * NPIX + pix] = v + (float)(ho - 1 + kk / 3);
                else
                    ppx[(b * KK9 + kk) * NPIX + pix] = v + (float)(wo - 1 + kk % 3);
            } else {
                int km = ch - 18;
                float v = acc[i][p] + b_mod[km];
                pmod[(b * KK9 + km) * NPIX + pix] = 1.f / (1.f + expf(-v));
            }
        }
    }
}

// ---------------------------------------------------------------------------
// Prep: w_dc -> bf16 hi/lo, kk-major chunks, XOR-swizzled k-octets so that a
// LINEAR global_load_lds produces a bank-conflict-free [hl][o128][32] layout.
// dst flat = ((ck*2+hl)*256 + o)*32 + klp ; source octet g = (klp>>3)^((o>>1)&3)
// ---------------------------------------------------------------------------
__global__ __launch_bounds__(256) void k_prep(
    const float* __restrict__ w_dc, unsigned short* __restrict__ wsplit)
{
    int idx = blockIdx.x * 256 + threadIdx.x;        // 589824 total
    int klp = idx & 31;
    int o = (idx >> 5) & 255;
    int rest = idx >> 13;                            // ck*2+hl
    int hl = rest & 1, ck = rest >> 1;
    int g = (klp >> 3) ^ ((o >> 1) & 3);             // XOR involution
    int kl = g * 8 + (klp & 7);
    int kp = ck * 32 + kl;                           // k' = kk*128 + c
    int kk = kp >> 7, c = kp & 127;
    float w = w_dc[o * KTOT + c * 9 + kk];
    unsigned short hi = f2bf(w);
    wsplit[idx] = hl ? f2bf(w - bf2f(hi)) : hi;
}

// ---------------------------------------------------------------------------
// Kernel B: pipelined fused sample + bf16x3 MFMA GEMM.
// Block: 128 o x 64 px, 4 waves (wo,wp) each 64o x 32px. W double-buffered
// (16KB/buf, swizzled), S single-buffered + register-carried (T14).
// Per chunk t: write S(t); issue W-gload(t+1); issue gathers(t+1);
// barrier; MFMA(t); consume gathers -> S-regs(t+1); vmcnt(0); barrier.
// ---------------------------------------------------------------------------
__global__ __launch_bounds__(256, 3) void k_main(
    const float* __restrict__ x, const unsigned short* __restrict__ wsplit,
    const float* __restrict__ ppy, const float* __restrict__ ppx,
    const float* __restrict__ pmod, float* __restrict__ out,
    float* __restrict__ gsum, float* __restrict__ gsq)
{
    __shared__ __align__(16) unsigned short Wsp[2][2 * 128 * 32]; // 32768 B
    __shared__ __align__(16) unsigned short Ssp[2 * 64 * SPAD];   // 10240 B
    __shared__ float ppl[3][KK9][64];                             // 6912 B
    __shared__ float red[2][128][2];                              // 2048 B

    const int t = threadIdx.x;
    const int b = blockIdx.x & 7;            // XCD-affine batch
    const int rem = blockIdx.x >> 3;         // 128
    const int oh = rem & 1;
    const int pix0 = (rem >> 1) * 64;
    const int lane = t & 63, wid = t >> 6;
    const int wo = wid >> 1, wp = wid & 1;
    const int o_lane = lane & 15, g4 = lane >> 4;
    const int pxl = t & 63, kg = t >> 6;

    for (int idx = t; idx < 3 * KK9 * 64; idx += 256) {
        int arr = idx / (KK9 * 64), rem2 = idx - arr * (KK9 * 64);
        int kk = rem2 >> 6, p = rem2 & 63;
        const float* src = (arr == 0) ? ppy : (arr == 1) ? ppx : pmod;
        ppl[arr][kk][p] = src[(b * KK9 + kk) * NPIX + pix0 + p];
    }
    __syncthreads();

    floatx4 acc[4][2] = {};
    const float* xb = x + b * CIN * NPIX;

    float sreg[8];
    float g00[8], g01[8], g10[8], g11[8];
    float w00, w01, w10, w11;
    int a00, a01, a10, a11;

    auto SETUP = [&](int kkv) {
        float py = ppl[0][kkv][pxl];
        float px = ppl[1][kkv][pxl];
        float m  = ppl[2][kkv][pxl];
        float y0f = floorf(py), x0f = floorf(px);
        float wy1 = py - y0f, wx1 = px - x0f;
        float wy0 = 1.f - wy1, wx0 = 1.f - wx1;
        int y0 = (int)y0f, x0 = (int)x0f;
        bool y0v = (unsigned)y0 < (unsigned)H_;
        bool y1v = (unsigned)(y0 + 1) < (unsigned)H_;
        bool x0v = (unsigned)x0 < (unsigned)W_;
        bool x1v = (unsigned)(x0 + 1) < (unsigned)W_;
        w00 = (y0v && x0v) ? wy0 * wx0 * m : 0.f;
        w01 = (y0v && x1v) ? wy0 * wx1 * m : 0.f;
        w10 = (y1v && x0v) ? wy1 * wx0 * m : 0.f;
        w11 = (y1v && x1v) ? wy1 * wx1 * m : 0.f;
        int y0c = min(max(y0, 0), H_ - 1), y1c = min(max(y0 + 1, 0), H_ - 1);
        int x0c = min(max(x0, 0), W_ - 1), x1c = min(max(x0 + 1, 0), W_ - 1);
        a00 = y0c * W_ + x0c; a01 = y0c * W_ + x1c;
        a10 = y1c * W_ + x0c; a11 = y1c * W_ + x1c;
    };
    auto GATHER = [&](int sub) {
        const float* pl = xb + (sub * 32 + kg * 8) * NPIX;
        #pragma unroll
        for (int j = 0; j < 8; ++j) {
            g00[j] = pl[a00]; g01[j] = pl[a01];
            g10[j] = pl[a10]; g11[j] = pl[a11];
            pl += NPIX;
        }
    };
    auto CONSUME = [&]() {
        #pragma unroll
        for (int j = 0; j < 8; ++j)
            sreg[j] = g00[j] * w00 + g01[j] * w01 + g10[j] * w10 + g11[j] * w11;
    };
    auto WRITES = [&]() {
        union { unsigned short u[8]; short8_t v; } ph, plo;
        #pragma unroll
        for (int j = 0; j < 8; ++j) {
            union { float f; unsigned u; } su; su.f = sreg[j];
            ph.u[j] = (unsigned short)(su.u >> 16);
            union { unsigned u; float f; } hf; hf.u = su.u & 0xFFFF0000u;
            union { float f; unsigned u; } du; du.f = sreg[j] - hf.f;
            plo.u[j] = (unsigned short)(du.u >> 16);
        }
        *(short8_t*)(Ssp + pxl * SPAD + kg * 8) = ph.v;
        *(short8_t*)(Ssp + 64 * SPAD + pxl * SPAD + kg * 8) = plo.v;
    };
    auto GLOADW = [&](int ck, int buf) {
        const unsigned short* wsrc = wsplit + ck * (2 * 256 * 32);
        #pragma unroll
        for (int i = 0; i < 4; ++i) {
            int j2 = wid * 4 + i;                 // 16 slices of 1KiB per buf
            int hl = j2 >> 3, js = j2 & 7;
            const unsigned short* src =
                wsrc + (hl * 256 + oh * 128) * 32 + js * 512 + lane * 8;
            unsigned short* dst = &Wsp[buf][hl * 4096 + js * 512];
#ifdef HAVE_GLOAD_LDS
            gload_lds16(src, dst);
#else
            *(float4*)(dst + lane * 8) = *(const float4*)src;
#endif
        }
    };
    auto MFMA_PHASE = [&](int buf) {
        short8_t bh[2], bl[2];
        #pragma unroll
        for (int ni = 0; ni < 2; ++ni) {
            int pxf = wp * 32 + ni * 16 + o_lane;
            bh[ni] = *(const short8_t*)(Ssp + pxf * SPAD + g4 * 8);
            bl[ni] = *(const short8_t*)(Ssp + 64 * SPAD + pxf * SPAD + g4 * 8);
        }
        const int gsw = (g4 ^ ((o_lane >> 1) & 3)) << 3;   // XOR swizzle
        #pragma unroll
        for (int mi = 0; mi < 4; ++mi) {
            int row = wo * 64 + mi * 16 + o_lane;
            const unsigned short* base = &Wsp[buf][row * 32 + gsw];
            short8_t ah = *(const short8_t*)base;
            short8_t al = *(const short8_t*)(base + 4096);
            #pragma unroll
            for (int ni = 0; ni < 2; ++ni) {
                acc[mi][ni] = __builtin_amdgcn_mfma_f32_16x16x32_bf16(
                    ah, bh[ni], acc[mi][ni], 0, 0, 0);
                acc[mi][ni] = __builtin_amdgcn_mfma_f32_16x16x32_bf16(
                    ah, bl[ni], acc[mi][ni], 0, 0, 0);
                acc[mi][ni] = __builtin_amdgcn_mfma_f32_16x16x32_bf16(
                    al, bh[ni], acc[mi][ni], 0, 0, 0);
            }
        }
    };

    // ---- prologue: W(0) + S(0)
    GLOADW(0, 0);
    SCHED0();
    SETUP(0);
    GATHER(0);
    CONSUME();           // drains gathers (and the older W gloads)

    // ---- main pipelined loop
    for (int tt = 0; tt < NCK - 1; ++tt) {
        int buf = tt & 1;
        WRITES();                         // publish S(tt)
        GLOADW(tt + 1, buf ^ 1);          // prefetch W(tt+1)
        SCHED0();                          // keep gloads older than gathers
        SETUP((tt + 1) >> 2);
        GATHER((tt + 1) & 3);
        WAIT_LGKM0();                     // own S writes retired
        SBAR(); SCHED0();                 // all S(tt) visible; W(tt) resident
        MFMA_PHASE(buf);
        CONSUME();                        // S-regs(tt+1); waits gathers
        WAIT_VM0();                       // W(tt+1) landed (flew during MFMA)
        SCHED0(); SBAR(); SCHED0();       // protect Ssp overwrite
    }
    // ---- tail chunk 35
    WRITES();
    WAIT_LGKM0();
    SBAR(); SCHED0();
    MFMA_PHASE(1);

    // ---- BN partial sums: reduce px (ni frags + lane bits 0-3)
    #pragma unroll
    for (int mi = 0; mi < 4; ++mi) {
        #pragma unroll
        for (int r = 0; r < 4; ++r) {
            float s = 0.f, q = 0.f;
            #pragma unroll
            for (int ni = 0; ni < 2; ++ni) {
                float v = acc[mi][ni][r];
                s += v; q += v * v;
            }
            s += __shfl_xor(s, 1); q += __shfl_xor(q, 1);
            s += __shfl_xor(s, 2); q += __shfl_xor(q, 2);
            s += __shfl_xor(s, 4); q += __shfl_xor(q, 4);
            s += __shfl_xor(s, 8); q += __shfl_xor(q, 8);
            if (o_lane == 0) {
                int ol = wo * 64 + mi * 16 + g4 * 4 + r;
                red[wp][ol][0] = s;
                red[wp][ol][1] = q;
            }
        }
    }
    __syncthreads();
    if (t < 128) {
        atomicAdd(&gsum[oh * 128 + t], red[0][t][0] + red[1][t][0]);
        atomicAdd(&gsq [oh * 128 + t], red[0][t][1] + red[1][t][1]);
    }

    // ---- store raw GEMM output
    #pragma unroll
    for (int mi = 0; mi < 4; ++mi) {
        int o_base = oh * 128 + wo * 64 + mi * 16 + g4 * 4;
        #pragma unroll
        for (int ni = 0; ni < 2; ++ni) {
            int px = pix0 + wp * 32 + ni * 16 + o_lane;
            #pragma unroll
            for (int r = 0; r < 4; ++r)
                out[(b * COUT + o_base + r) * NPIX + px] = acc[mi][ni][r];
        }
    }
}

// ---------------------------------------------------------------------------
// Kernel C: in-place BN + affine + SiLU, float4.
// ---------------------------------------------------------------------------
__global__ __launch_bounds__(256) void k_bnact(
    float* __restrict__ out, const float* __restrict__ gsum,
    const float* __restrict__ gsq, const float* __restrict__ gamma,
    const float* __restrict__ beta)
{
    int idx = blockIdx.x * 256 + threadIdx.x;
    int o = (idx >> 10) & 255;
    const float invn = 1.f / 32768.f;
    float mean = gsum[o] * invn;
    float var = gsq[o] * invn - mean * mean;
    float scale = gamma[o] * rsqrtf(var + 1e-5f);
    float shift = beta[o] - mean * scale;
    float4* p = (float4*)out;
    float4 v = p[idx];
    float y;
    y = v.x * scale + shift; v.x = y / (1.f + expf(-y));
    y = v.y * scale + shift; v.y = y / (1.f + expf(-y));
    y = v.z * scale + shift; v.z = y / (1.f + expf(-y));
    y = v.w * scale + shift; v.w = y / (1.f + expf(-y));
    p[idx] = v;
}

extern "C" void kernel_launch(void* const* d_in, const int* in_sizes, int n_in,
                              void* d_out, int out_size, void* d_ws, size_t ws_size,
                              hipStream_t stream)
{
    (void)in_sizes; (void)n_in; (void)out_size; (void)ws_size;
    const float* x     = (const float*)d_in[0];
    const float* w_off = (const float*)d_in[1];
    const float* b_off = (const float*)d_in[2];
    const float* w_mod = (const float*)d_in[3];
    const float* b_mod = (const float*)d_in[4];
    const float* w_dc  = (const float*)d_in[5];
    const float* gamma = (const float*)d_in[6];
    const float* beta  = (const float*)d_in[7];
    float* out = (float*)d_out;
    float* ws  = (float*)d_ws;

    const int NPK = NB * KK9 * NPIX;              // 294912
    float* ppy  = ws;
    float* ppx  = ws + NPK;
    float* pmod = ws + 2 * NPK;
    unsigned short* wsplit = (unsigned short*)(ws + 3 * NPK);  // 589824 shorts
    float* gsum = ws + 3 * NPK + 294912;
    float* gsq  = gsum + 256;

    hipMemsetAsync(gsum, 0, 512 * sizeof(float), stream);
    hipLaunchKernelGGL(k_offmod, dim3(8, 8, NB), dim3(256), 0, stream,
                       x, w_off, b_off, w_mod, b_mod, ppy, ppx, pmod);
    hipLaunchKernelGGL(k_prep, dim3(2304), dim3(256), 0, stream,
                       w_dc, wsplit);
    hipLaunchKernelGGL(k_main, dim3(1024), dim3(256), 0, stream,
                       x, wsplit, ppy, ppx, pmod, out, gsum, gsq);
    hipLaunchKernelGGL(k_bnact, dim3(8192), dim3(256), 0, stream,
                       out, gsum, gsq, gamma, beta);
}

// Round 8
// 290.272 us; speedup vs baseline: 1.3614x; 1.3614x over previous
//
#include <hip/hip_runtime.h>
#include <hip/hip_bf16.h>
#include <math.h>

#define H_ 64
#define W_ 64
#define CIN 128
#define COUT 256
#define NB 8
#define KK9 9
#define NPIX 4096        // H_*W_
#define KTOT 1152        // CIN*KK9
#define NCK 36           // K chunks of 32 (kk-major: k' = kk*128 + c)
#define SPAD 40          // S K-row pad (shorts): 80B rows
#define OSP 40           // off2 S row pad

typedef short short8_t __attribute__((ext_vector_type(8)));
typedef float floatx4 __attribute__((ext_vector_type(4)));

__device__ __forceinline__ unsigned short f2bf(float f) {
    union { float f; unsigned u; } v; v.f = f;
    unsigned r = v.u + 0x7FFF + ((v.u >> 16) & 1);   // RNE
    return (unsigned short)(r >> 16);
}
__device__ __forceinline__ float bf2f(unsigned short h) {
    union { unsigned u; float f; } v; v.u = ((unsigned)h) << 16;
    return v.f;
}

// ---------------------------------------------------------------------------
// Prep A: w_dc [256][1152] -> bf16 hi/lo, kk-major chunks.
// flat = ((ck*2+hl)*256 + o)*32 + kl ; k' = ck*32+kl = kk*128 + c.
// ---------------------------------------------------------------------------
__global__ __launch_bounds__(256) void k_prep_dc(
    const float* __restrict__ w_dc, unsigned short* __restrict__ wsplit)
{
    int idx = blockIdx.x * 256 + threadIdx.x;        // 589824 total
    int kl = idx & 31;
    int o  = (idx >> 5) & 255;
    int rest = idx >> 13;                            // ck*2+hl
    int hl = rest & 1, ck = rest >> 1;
    int kp = ck * 32 + kl;
    int kk = kp >> 7, c = kp & 127;
    float w = w_dc[o * KTOT + c * 9 + kk];
    unsigned short hi = f2bf(w);
    wsplit[idx] = hl ? f2bf(w - bf2f(hi)) : hi;
}

// ---------------------------------------------------------------------------
// Prep B: w_off (18 rows) + w_mod (9 rows) + 5 zero rows -> M=32 GEMM A,
// same kk-major hi/lo layout: flat = ((ck*2+hl)*32 + o)*32 + kl.
// ---------------------------------------------------------------------------
__global__ __launch_bounds__(256) void k_prep_om(
    const float* __restrict__ w_off, const float* __restrict__ w_mod,
    unsigned short* __restrict__ womsplit)
{
    int idx = blockIdx.x * 256 + threadIdx.x;        // 73728 total
    int kl = idx & 31;
    int o  = (idx >> 5) & 31;
    int rest = idx >> 10;                            // ck*2+hl
    int hl = rest & 1, ck = rest >> 1;
    int kp = ck * 32 + kl;
    int kk = kp >> 7, c = kp & 127;
    float w = 0.f;
    if (o < 18)      w = w_off[(o * CIN + c) * 9 + kk];
    else if (o < 27) w = w_mod[((o - 18) * CIN + c) * 9 + kk];
    unsigned short hi = f2bf(w);
    womsplit[idx] = hl ? f2bf(w - bf2f(hi)) : hi;
}

// ---------------------------------------------------------------------------
// Kernel A': offset+mod conv as bf16 MFMA GEMM (M=32, N=32768, K=1152).
// Integer-shift sampling (zero-pad border), S single-bf16, W hi/lo (bf16x2).
// Block: 256 px, 4 waves x 64 px; S double-buffered, 1 barrier/chunk;
// W frags direct global->reg. Epilogue: bias + base-grid / sigmoid.
// GRID: 8 batches x 16 px-tiles = 128 blocks  (r7 bug: was 1024 -> OOB).
// ---------------------------------------------------------------------------
__global__ __launch_bounds__(256, 4) void k_off2(
    const float* __restrict__ x, const unsigned short* __restrict__ womsplit,
    const float* __restrict__ b_off, const float* __restrict__ b_mod,
    float* __restrict__ ppy, float* __restrict__ ppx, float* __restrict__ pmod)
{
    __shared__ __align__(16) unsigned short S2[2][256 * OSP];   // 40960 B

    const int t = threadIdx.x;
    const int b = blockIdx.x & 7;                  // XCD-affine batch
    const int pix0 = (blockIdx.x >> 3) * 256;      // blockIdx>>3 in [0,16)
    const int lane = t & 63, wid = t >> 6;
    const int o_lane = lane & 15, g4 = lane >> 4;

    const float* xb = x + b * CIN * NPIX;
    const int pix = pix0 + t;                      // this thread's pixel
    const int ho = pix >> 6, wo2 = pix & 63;

    floatx4 acc[2][4] = {};
    float g[32];
    int addr = 0; float wmask = 0.f;

    auto SETUP2 = [&](int kkv) {
        int sy = ho + (kkv / 3) - 1, sx = wo2 + (kkv % 3) - 1;
        bool v = ((unsigned)sy < (unsigned)H_) && ((unsigned)sx < (unsigned)W_);
        wmask = v ? 1.f : 0.f;
        addr = min(max(sy, 0), H_ - 1) * W_ + min(max(sx, 0), W_ - 1);
    };
    auto GATH2 = [&](int ck) {
        const float* pl = xb + ((ck & 3) * 32) * NPIX + addr;
        #pragma unroll
        for (int j = 0; j < 32; ++j) { g[j] = pl[0]; pl += NPIX; }
    };
    auto WR2 = [&](int buf) {
        #pragma unroll
        for (int q = 0; q < 4; ++q) {
            union { unsigned short u[8]; short8_t v; } p;
            #pragma unroll
            for (int j = 0; j < 8; ++j) p.u[j] = f2bf(g[q * 8 + j] * wmask);
            *(short8_t*)(&S2[buf][t * OSP + q * 8]) = p.v;
        }
    };

    SETUP2(0); GATH2(0); WR2(0);
    __syncthreads();

    for (int tt = 0; tt < NCK; ++tt) {
        // 1. W frags (issued first so MFMA's vmcnt wait leaves gathers in flight)
        short8_t ah[2], al[2];
        #pragma unroll
        for (int mi = 0; mi < 2; ++mi) {
            const unsigned short* wb_ =
                womsplit + ((tt * 2 + 0) * 32 + mi * 16 + o_lane) * 32 + g4 * 8;
            ah[mi] = *(const short8_t*)wb_;
            al[mi] = *(const short8_t*)(wb_ + 1024);   // hl=1 block
        }
        // 2. next-chunk gathers
        if (tt + 1 < NCK) { SETUP2((tt + 1) >> 2); GATH2(tt + 1); }
        // 3. S frags + MFMA (bf16x2: (Whi+Wlo)*S)
        #pragma unroll
        for (int ni = 0; ni < 4; ++ni) {
            int pxf = wid * 64 + ni * 16 + o_lane;
            short8_t bb = *(const short8_t*)(&S2[tt & 1][pxf * OSP + g4 * 8]);
            #pragma unroll
            for (int mi = 0; mi < 2; ++mi) {
                acc[mi][ni] = __builtin_amdgcn_mfma_f32_16x16x32_bf16(
                    ah[mi], bb, acc[mi][ni], 0, 0, 0);
                acc[mi][ni] = __builtin_amdgcn_mfma_f32_16x16x32_bf16(
                    al[mi], bb, acc[mi][ni], 0, 0, 0);
            }
        }
        // 4. publish next S
        if (tt + 1 < NCK) WR2((tt + 1) & 1);
        __syncthreads();
    }

    // epilogue: o = mi*16 + g4*4 + r ; pix = pix0 + wid*64 + ni*16 + o_lane
    #pragma unroll
    for (int mi = 0; mi < 2; ++mi) {
        #pragma unroll
        for (int r = 0; r < 4; ++r) {
            int o = mi * 16 + g4 * 4 + r;
            if (o >= 27) continue;
            #pragma unroll
            for (int ni = 0; ni < 4; ++ni) {
                int pp = pix0 + wid * 64 + ni * 16 + o_lane;
                float v = acc[mi][ni][r];
                int hoo = pp >> 6, woo = pp & 63;
                if (o < 18) {
                    int kk2 = o >> 1;
                    float vv = v + b_off[o];
                    if ((o & 1) == 0)
                        ppy[(b * KK9 + kk2) * NPIX + pp] = vv + (float)(hoo - 1 + kk2 / 3);
                    else
                        ppx[(b * KK9 + kk2) * NPIX + pp] = vv + (float)(woo - 1 + kk2 % 3);
                } else {
                    int km = o - 18;
                    float vv = v + b_mod[km];
                    pmod[(b * KK9 + km) * NPIX + pp] = 1.f / (1.f + expf(-vv));
                }
            }
        }
    }
}

// ---------------------------------------------------------------------------
// Kernel B: fused bilinear-sample + bf16x3 MFMA GEMM (M=256,N=32768,K=1152).
// Block: 256 o x 64 px, 4 waves x 64 o each (no sampling duplication).
// W: direct global->reg frags (no LDS, no staging barrier). S: LDS dbuf,
// ONE __syncthreads per chunk; gathers(t+1) fly under MFMA(t).
// ---------------------------------------------------------------------------
__global__ __launch_bounds__(256, 3) void k_main(
    const float* __restrict__ x, const unsigned short* __restrict__ wsplit,
    const float* __restrict__ ppy, const float* __restrict__ ppx,
    const float* __restrict__ pmod, float* __restrict__ out,
    float* __restrict__ gsum, float* __restrict__ gsq)
{
    __shared__ __align__(16) unsigned short Ssp[2][2 * 64 * SPAD]; // 20480 B
    __shared__ float ppl[3][KK9][64];                              // 6912 B

    const int t = threadIdx.x;
    const int b = blockIdx.x & 7;                  // XCD-affine batch
    const int pix0 = (blockIdx.x >> 3) * 64;
    const int lane = t & 63, wid = t >> 6;
    const int o_lane = lane & 15, g4 = lane >> 4;
    const int pxl = t & 63, kg = t >> 6;

    for (int idx = t; idx < 3 * KK9 * 64; idx += 256) {
        int arr = idx / (KK9 * 64), rem2 = idx - arr * (KK9 * 64);
        int kk = rem2 >> 6, p = rem2 & 63;
        const float* src = (arr == 0) ? ppy : (arr == 1) ? ppx : pmod;
        ppl[arr][kk][p] = src[(b * KK9 + kk) * NPIX + pix0 + p];
    }
    __syncthreads();

    floatx4 acc[4][4] = {};
    const float* xb = x + b * CIN * NPIX;

    float g00[8], g01[8], g10[8], g11[8];
    float w00, w01, w10, w11;
    int a00, a01, a10, a11;

    auto SETUP = [&](int kkv) {
        float py = ppl[0][kkv][pxl];
        float px = ppl[1][kkv][pxl];
        float m  = ppl[2][kkv][pxl];
        float y0f = floorf(py), x0f = floorf(px);
        float wy1 = py - y0f, wx1 = px - x0f;
        float wy0 = 1.f - wy1, wx0 = 1.f - wx1;
        int y0 = (int)y0f, x0 = (int)x0f;
        bool y0v = (unsigned)y0 < (unsigned)H_;
        bool y1v = (unsigned)(y0 + 1) < (unsigned)H_;
        bool x0v = (unsigned)x0 < (unsigned)W_;
        bool x1v = (unsigned)(x0 + 1) < (unsigned)W_;
        w00 = (y0v && x0v) ? wy0 * wx0 * m : 0.f;
        w01 = (y0v && x1v) ? wy0 * wx1 * m : 0.f;
        w10 = (y1v && x0v) ? wy1 * wx0 * m : 0.f;
        w11 = (y1v && x1v) ? wy1 * wx1 * m : 0.f;
        int y0c = min(max(y0, 0), H_ - 1), y1c = min(max(y0 + 1, 0), H_ - 1);
        int x0c = min(max(x0, 0), W_ - 1), x1c = min(max(x0 + 1, 0), W_ - 1);
        a00 = y0c * W_ + x0c; a01 = y0c * W_ + x1c;
        a10 = y1c * W_ + x0c; a11 = y1c * W_ + x1c;
    };
    auto GATHER = [&](int ck) {
        const float* pl = xb + ((ck & 3) * 32 + kg * 8) * NPIX;
        #pragma unroll
        for (int j = 0; j < 8; ++j) {
            g00[j] = pl[a00]; g01[j] = pl[a01];
            g10[j] = pl[a10]; g11[j] = pl[a11];
            pl += NPIX;
        }
    };
    auto WRITES = [&](int buf) {   // consume gathers -> split -> publish
        union { unsigned short u[8]; short8_t v; } ph, plo;
        #pragma unroll
        for (int j = 0; j < 8; ++j) {
            float s = g00[j] * w00 + g01[j] * w01 + g10[j] * w10 + g11[j] * w11;
            union { float f; unsigned u; } su; su.f = s;
            ph.u[j] = (unsigned short)(su.u >> 16);
            union { unsigned u; float f; } hf; hf.u = su.u & 0xFFFF0000u;
            union { float f; unsigned u; } du; du.f = s - hf.f;
            plo.u[j] = (unsigned short)(du.u >> 16);
        }
        *(short8_t*)(&Ssp[buf][pxl * SPAD + kg * 8]) = ph.v;
        *(short8_t*)(&Ssp[buf][64 * SPAD + pxl * SPAD + kg * 8]) = plo.v;
    };

    SETUP(0); GATHER(0); WRITES(0);
    __syncthreads();

    for (int tt = 0; tt < NCK; ++tt) {
        // 1. W frags for this chunk (8 x b128 global, L2-hot; issued first)
        short8_t ah[4], al[4];
        #pragma unroll
        for (int mi = 0; mi < 4; ++mi) {
            const unsigned short* wb_ =
                wsplit + ((tt * 2 + 0) * 256 + wid * 64 + mi * 16 + o_lane) * 32 + g4 * 8;
            ah[mi] = *(const short8_t*)wb_;
            al[mi] = *(const short8_t*)(wb_ + 8192);   // hl=1 block
        }
        // 2. issue next-chunk gathers (fly under this chunk's MFMA)
        if (tt + 1 < NCK) { SETUP((tt + 1) >> 2); GATHER(tt + 1); }
        // 3. S frags + 48 MFMA (bf16x3)
        #pragma unroll
        for (int ni = 0; ni < 4; ++ni) {
            int pxf = ni * 16 + o_lane;
            short8_t bh = *(const short8_t*)(&Ssp[tt & 1][pxf * SPAD + g4 * 8]);
            short8_t bl = *(const short8_t*)(&Ssp[tt & 1][64 * SPAD + pxf * SPAD + g4 * 8]);
            #pragma unroll
            for (int mi = 0; mi < 4; ++mi) {
                acc[mi][ni] = __builtin_amdgcn_mfma_f32_16x16x32_bf16(
                    ah[mi], bh, acc[mi][ni], 0, 0, 0);
                acc[mi][ni] = __builtin_amdgcn_mfma_f32_16x16x32_bf16(
                    ah[mi], bl, acc[mi][ni], 0, 0, 0);
                acc[mi][ni] = __builtin_amdgcn_mfma_f32_16x16x32_bf16(
                    al[mi], bh, acc[mi][ni], 0, 0, 0);
            }
        }
        // 4. publish next S into the other buffer
        if (tt + 1 < NCK) WRITES((tt + 1) & 1);
        __syncthreads();
    }

    // ---- BN partials: sum px (4 ni in-lane + butterfly lane bits 0-3)
    #pragma unroll
    for (int mi = 0; mi < 4; ++mi) {
        #pragma unroll
        for (int r = 0; r < 4; ++r) {
            float s = 0.f, q = 0.f;
            #pragma unroll
            for (int ni = 0; ni < 4; ++ni) {
                float v = acc[mi][ni][r];
                s += v; q += v * v;
            }
            s += __shfl_xor(s, 1); q += __shfl_xor(q, 1);
            s += __shfl_xor(s, 2); q += __shfl_xor(q, 2);
            s += __shfl_xor(s, 4); q += __shfl_xor(q, 4);
            s += __shfl_xor(s, 8); q += __shfl_xor(q, 8);
            if (o_lane == 0) {
                int o = wid * 64 + mi * 16 + g4 * 4 + r;
                atomicAdd(&gsum[o], s);
                atomicAdd(&gsq[o],  q);
            }
        }
    }

    // ---- store raw GEMM output
    #pragma unroll
    for (int mi = 0; mi < 4; ++mi) {
        int o_base = wid * 64 + mi * 16 + g4 * 4;
        #pragma unroll
        for (int ni = 0; ni < 4; ++ni) {
            int px = pix0 + ni * 16 + o_lane;
            #pragma unroll
            for (int r = 0; r < 4; ++r)
                out[(b * COUT + o_base + r) * NPIX + px] = acc[mi][ni][r];
        }
    }
}

// ---------------------------------------------------------------------------
// Kernel C: in-place BN + affine + SiLU, float4.
// ---------------------------------------------------------------------------
__global__ __launch_bounds__(256) void k_bnact(
    float* __restrict__ out, const float* __restrict__ gsum,
    const float* __restrict__ gsq, const float* __restrict__ gamma,
    const float* __restrict__ beta)
{
    int idx = blockIdx.x * 256 + threadIdx.x;
    int o = (idx >> 10) & 255;
    const float invn = 1.f / 32768.f;
    float mean = gsum[o] * invn;
    float var = gsq[o] * invn - mean * mean;
    float scale = gamma[o] * rsqrtf(var + 1e-5f);
    float shift = beta[o] - mean * scale;
    float4* p = (float4*)out;
    float4 v = p[idx];
    float y;
    y = v.x * scale + shift; v.x = y / (1.f + expf(-y));
    y = v.y * scale + shift; v.y = y / (1.f + expf(-y));
    y = v.z * scale + shift; v.z = y / (1.f + expf(-y));
    y = v.w * scale + shift; v.w = y / (1.f + expf(-y));
    p[idx] = v;
}

extern "C" void kernel_launch(void* const* d_in, const int* in_sizes, int n_in,
                              void* d_out, int out_size, void* d_ws, size_t ws_size,
                              hipStream_t stream)
{
    (void)in_sizes; (void)n_in; (void)out_size; (void)ws_size;
    const float* x     = (const float*)d_in[0];
    const float* w_off = (const float*)d_in[1];
    const float* b_off = (const float*)d_in[2];
    const float* w_mod = (const float*)d_in[3];
    const float* b_mod = (const float*)d_in[4];
    const float* w_dc  = (const float*)d_in[5];
    const float* gamma = (const float*)d_in[6];
    const float* beta  = (const float*)d_in[7];
    float* out = (float*)d_out;
    float* ws  = (float*)d_ws;

    const int NPK = NB * KK9 * NPIX;              // 294912
    float* ppy  = ws;
    float* ppx  = ws + NPK;
    float* pmod = ws + 2 * NPK;
    unsigned short* wsplit   = (unsigned short*)(ws + 3 * NPK);          // 589824 shorts
    unsigned short* womsplit = (unsigned short*)(ws + 3 * NPK + 294912); // 73728 shorts
    float* gsum = ws + 3 * NPK + 294912 + 36864;
    float* gsq  = gsum + 256;

    hipMemsetAsync(gsum, 0, 512 * sizeof(float), stream);
    hipLaunchKernelGGL(k_prep_dc, dim3(2304), dim3(256), 0, stream, w_dc, wsplit);
    hipLaunchKernelGGL(k_prep_om, dim3(288), dim3(256), 0, stream,
                       w_off, w_mod, womsplit);
    hipLaunchKernelGGL(k_off2, dim3(128), dim3(256), 0, stream,
                       x, womsplit, b_off, b_mod, ppy, ppx, pmod);
    hipLaunchKernelGGL(k_main, dim3(512), dim3(256), 0, stream,
                       x, wsplit, ppy, ppx, pmod, out, gsum, gsq);
    hipLaunchKernelGGL(k_bnact, dim3(8192), dim3(256), 0, stream,
                       out, gsum, gsq, gamma, beta);
}